// Round 1
// baseline (1338.078 us; speedup 1.0000x reference)
//
#include <hip/hip_runtime.h>
#include <hip/hip_bf16.h>

// KNN (K=8) + inverse-distance-weighted average.
// data1: [N=4096, D=1024] fp32, data2: [M=8192, D=1024] fp32, out: [N, D] fp32.
//
// Plan:
//  A) y2[m] = ||data2[m]||^2
//  B) fp32 tiled GEMM computing s = y2[c] - 2*dot(data1[r], data2[c]) per
//     (row, col); per-row top-8 (smallest s) maintained per 1024-col chunk.
//     Ranking by s == ranking by d2 since x2[r] is constant per row.
//  C) per row: merge 8 chunk-lists (64 candidates) -> global top-8,
//     w = 1/(sqrt(x2+s)+0.1), out = sum(w * data2[idx]) / sum(w).

#define BKK 32
#define SENTINEL 1e30f

__global__ __launch_bounds__(256) void rownorm_kernel(
    const float* __restrict__ B, float* __restrict__ y2) {
  const int m = blockIdx.x;
  const int tid = threadIdx.x;
  __shared__ float red[256];
  const float4 v = *(const float4*)&B[(size_t)m * 1024 + tid * 4];
  red[tid] = v.x * v.x + v.y * v.y + v.z * v.z + v.w * v.w;
  __syncthreads();
  for (int s = 128; s > 0; s >>= 1) {
    if (tid < s) red[tid] += red[tid + s];
    __syncthreads();
  }
  if (tid == 0) y2[m] = red[0];
}

// Grid: (M/1024 chunks, N/64 row-tiles). Block: 256 threads (16x16).
__global__ __launch_bounds__(256) void knn_chunk_kernel(
    const float* __restrict__ A, const float* __restrict__ B,
    const float* __restrict__ y2g,
    float* __restrict__ cand_s, int* __restrict__ cand_i) {
  __shared__ float As[BKK][68];  // [k][row], stride 68 keeps 16B alignment
  __shared__ float Bs[BKK][68];  // [k][col]
  __shared__ float Sc[64][65];   // score tile [row][col]

  const int tid = threadIdx.x;
  const int tx = tid & 15;        // col group
  const int ty = tid >> 4;        // row group
  const int r0 = blockIdx.y * 64;
  const int c0 = blockIdx.x * 1024;

  const int lrow = tid >> 3;       // 0..31 (staging row)
  const int lk = (tid & 7) * 4;    // 0,4,...,28 (staging k)

  // per-row top-8, owned by threads 0..63 (row = r0 + tid)
  float top_s[8];
  int top_i[8];
#pragma unroll
  for (int j = 0; j < 8; ++j) { top_s[j] = SENTINEL; top_i[j] = 0x7fffffff; }

  for (int tile = 0; tile < 16; ++tile) {
    const int cbase = c0 + tile * 64;
    float acc[4][4];
#pragma unroll
    for (int i = 0; i < 4; ++i)
#pragma unroll
      for (int j = 0; j < 4; ++j) acc[i][j] = 0.0f;

    for (int k0 = 0; k0 < 1024; k0 += BKK) {
      const float4 a0 = *(const float4*)&A[(size_t)(r0 + lrow) * 1024 + k0 + lk];
      const float4 a1 = *(const float4*)&A[(size_t)(r0 + lrow + 32) * 1024 + k0 + lk];
      const float4 b0 = *(const float4*)&B[(size_t)(cbase + lrow) * 1024 + k0 + lk];
      const float4 b1 = *(const float4*)&B[(size_t)(cbase + lrow + 32) * 1024 + k0 + lk];
      __syncthreads();  // previous tile's LDS readers done
      As[lk + 0][lrow] = a0.x; As[lk + 1][lrow] = a0.y;
      As[lk + 2][lrow] = a0.z; As[lk + 3][lrow] = a0.w;
      As[lk + 0][lrow + 32] = a1.x; As[lk + 1][lrow + 32] = a1.y;
      As[lk + 2][lrow + 32] = a1.z; As[lk + 3][lrow + 32] = a1.w;
      Bs[lk + 0][lrow] = b0.x; Bs[lk + 1][lrow] = b0.y;
      Bs[lk + 2][lrow] = b0.z; Bs[lk + 3][lrow] = b0.w;
      Bs[lk + 0][lrow + 32] = b1.x; Bs[lk + 1][lrow + 32] = b1.y;
      Bs[lk + 2][lrow + 32] = b1.z; Bs[lk + 3][lrow + 32] = b1.w;
      __syncthreads();
#pragma unroll
      for (int kk = 0; kk < BKK; ++kk) {
        const float4 av = *(const float4*)&As[kk][ty * 4];
        const float4 bv = *(const float4*)&Bs[kk][tx * 4];
        acc[0][0] += av.x * bv.x; acc[0][1] += av.x * bv.y;
        acc[0][2] += av.x * bv.z; acc[0][3] += av.x * bv.w;
        acc[1][0] += av.y * bv.x; acc[1][1] += av.y * bv.y;
        acc[1][2] += av.y * bv.z; acc[1][3] += av.y * bv.w;
        acc[2][0] += av.z * bv.x; acc[2][1] += av.z * bv.y;
        acc[2][2] += av.z * bv.z; acc[2][3] += av.z * bv.w;
        acc[3][0] += av.w * bv.x; acc[3][1] += av.w * bv.y;
        acc[3][2] += av.w * bv.z; acc[3][3] += av.w * bv.w;
      }
    }
    // epilogue: scores into Sc (safe: prior scan finished before this tile's
    // first __syncthreads in the k-loop)
#pragma unroll
    for (int i = 0; i < 4; ++i) {
      const int row = ty * 4 + i;
#pragma unroll
      for (int j = 0; j < 4; ++j) {
        const int col = tx * 4 + j;
        Sc[row][col] = y2g[cbase + col] - 2.0f * acc[i][j];
      }
    }
    __syncthreads();
    if (tid < 64) {
      for (int c = 0; c < 64; ++c) {
        const float s = Sc[tid][c];
        if (s < top_s[7]) {  // strict <: keeps smaller index on ties
          top_s[7] = s; top_i[7] = cbase + c;
#pragma unroll
          for (int j = 7; j > 0; --j) {
            if (top_s[j] < top_s[j - 1]) {
              const float ts = top_s[j]; top_s[j] = top_s[j - 1]; top_s[j - 1] = ts;
              const int ti = top_i[j]; top_i[j] = top_i[j - 1]; top_i[j - 1] = ti;
            }
          }
        }
      }
    }
    // no trailing sync needed: next tile's LDS writes are behind a sync
  }

  if (tid < 64) {
    const int n = r0 + tid;
    const int base = (n * gridDim.x + blockIdx.x) * 8;
#pragma unroll
    for (int j = 0; j < 8; ++j) {
      cand_s[base + j] = top_s[j];
      cand_i[base + j] = top_i[j];
    }
  }
}

// Grid: N blocks. Merge 64 candidates -> top-8, weighted gather.
__global__ __launch_bounds__(256) void finalize_kernel(
    const float* __restrict__ A, const float* __restrict__ B,
    const float* __restrict__ cand_s, const int* __restrict__ cand_i,
    float* __restrict__ out, int nchunks) {
  const int n = blockIdx.x;
  const int tid = threadIdx.x;
  __shared__ float red[256];
  __shared__ float ls[64];
  __shared__ int li[64];
  __shared__ float wsh[8];
  __shared__ int wid[8];
  __shared__ float wsum_sh;

  const int ncand = nchunks * 8;  // 64
  const float4 a = *(const float4*)&A[(size_t)n * 1024 + tid * 4];
  red[tid] = a.x * a.x + a.y * a.y + a.z * a.z + a.w * a.w;
  if (tid < ncand) {
    ls[tid] = cand_s[n * ncand + tid];
    li[tid] = cand_i[n * ncand + tid];
  }
  __syncthreads();
  for (int s = 128; s > 0; s >>= 1) {
    if (tid < s) red[tid] += red[tid + s];
    __syncthreads();
  }
  if (tid == 0) {
    const float x2 = red[0];
    float wsum = 0.0f;
    for (int j = 0; j < 8; ++j) {
      float bs = SENTINEL;
      int bi = 0x7fffffff;
      int bp = 0;
      for (int c = 0; c < ncand; ++c) {
        const float s_ = ls[c];
        const int i_ = li[c];
        if (s_ < bs || (s_ == bs && i_ < bi)) { bs = s_; bi = i_; bp = c; }
      }
      ls[bp] = SENTINEL; li[bp] = 0x7fffffff;
      float d2 = x2 + bs;
      d2 = fmaxf(d2, 1e-12f);
      const float wk = 1.0f / (sqrtf(d2) + 0.1f);
      wsh[j] = wk; wid[j] = bi;
      wsum += wk;
    }
    wsum_sh = wsum;
  }
  __syncthreads();
  const float inv = 1.0f / wsum_sh;
  float ox = 0.0f, oy = 0.0f, oz = 0.0f, ow = 0.0f;
#pragma unroll
  for (int j = 0; j < 8; ++j) {
    const float wk = wsh[j];
    const float4 v = *(const float4*)&B[(size_t)wid[j] * 1024 + tid * 4];
    ox += wk * v.x; oy += wk * v.y; oz += wk * v.z; ow += wk * v.w;
  }
  float4 o;
  o.x = ox * inv; o.y = oy * inv; o.z = oz * inv; o.w = ow * inv;
  *(float4*)&out[(size_t)n * 1024 + tid * 4] = o;
}

extern "C" void kernel_launch(void* const* d_in, const int* in_sizes, int n_in,
                              void* d_out, int out_size, void* d_ws, size_t ws_size,
                              hipStream_t stream) {
  const float* A = (const float*)d_in[0];   // data1 [N, 1024]
  const float* Bm = (const float*)d_in[1];  // data2 [M, 1024]
  const int D = 1024;
  const int N = in_sizes[0] / D;  // 4096
  const int M = in_sizes[1] / D;  // 8192
  const int nchunks = M / 1024;   // 8

  float* y2 = (float*)d_ws;                        // M floats
  float* cand_s = y2 + M;                          // N*64 floats
  int* cand_i = (int*)(cand_s + (size_t)N * 64);   // N*64 ints

  rownorm_kernel<<<M, 256, 0, stream>>>(Bm, y2);
  dim3 gridB(nchunks, N / 64);
  knn_chunk_kernel<<<gridB, 256, 0, stream>>>(A, Bm, y2, cand_s, cand_i);
  finalize_kernel<<<N, 256, 0, stream>>>(A, Bm, cand_s, cand_i, (float*)d_out,
                                         nchunks);
}

// Round 2
// 365.975 us; speedup vs baseline: 3.6562x; 3.6562x over previous
//
#include <hip/hip_runtime.h>

// KNN (K=8) + inverse-distance-weighted average, MFMA screening version.
// data1: [N=4096, D=1024] fp32, data2: [M=8192, D=1024] fp32, out: [N, D] fp32.
//
// Fast path:
//  1) convert A,B -> bf16 (RNE)
//  2) y2[m] = ||B[m]||^2 (fp32)
//  3) screen: bf16 MFMA GEMM (128x128 tiles, 16x16x32), approx score
//     s = y2[c] - 2*dot_bf16; fused per-row top-8 per 128-col half-chunk.
//     Approx d2 error (~±0.25 @3sigma) << top-8 gap (~2.8) -> true top-8
//     survives screening with overwhelming probability.
//  4) finalize: merge 512 candidates -> approx top-16 -> EXACT fp32 rescore
//     -> top-8 by (d2, idx) -> weights w=1/(sqrt(max(d2,1e-12))+0.1) -> gather.
// Fallback (small ws): round-1 pure-fp32 path (verified correct).

typedef short bf16x8 __attribute__((ext_vector_type(8)));
typedef float f32x4 __attribute__((ext_vector_type(4)));

#define SENTINEL 1e30f
#define BKK 32

// ---------------- shared: row norms ----------------
__global__ __launch_bounds__(256) void rownorm_kernel(
    const float* __restrict__ B, float* __restrict__ y2) {
  const int m = blockIdx.x;
  const int tid = threadIdx.x;
  __shared__ float red[256];
  const float4 v = *(const float4*)&B[(size_t)m * 1024 + tid * 4];
  red[tid] = v.x * v.x + v.y * v.y + v.z * v.z + v.w * v.w;
  __syncthreads();
  for (int s = 128; s > 0; s >>= 1) {
    if (tid < s) red[tid] += red[tid + s];
    __syncthreads();
  }
  if (tid == 0) y2[m] = red[0];
}

// ---------------- fast path kernels ----------------
__global__ __launch_bounds__(256) void convert_bf16_kernel(
    const float* __restrict__ src, unsigned short* __restrict__ dst, int n4) {
  const int i = blockIdx.x * 256 + threadIdx.x;
  if (i >= n4) return;
  const float4 v = ((const float4*)src)[i];
  ushort4 o;
  unsigned u;
  u = __float_as_uint(v.x); o.x = (unsigned short)((u + 0x7fffu + ((u >> 16) & 1u)) >> 16);
  u = __float_as_uint(v.y); o.y = (unsigned short)((u + 0x7fffu + ((u >> 16) & 1u)) >> 16);
  u = __float_as_uint(v.z); o.z = (unsigned short)((u + 0x7fffu + ((u >> 16) & 1u)) >> 16);
  u = __float_as_uint(v.w); o.w = (unsigned short)((u + 0x7fffu + ((u >> 16) & 1u)) >> 16);
  ((ushort4*)dst)[i] = o;
}

// grid: (M/256 chunks, N/128 row tiles), 256 threads = 4 waves (2x2).
// Per wave: 64x64 quadrant, 4x4 fragments of 16x16x32 bf16 MFMA.
__global__ __launch_bounds__(256) void screen_kernel(
    const unsigned short* __restrict__ Abf, const unsigned short* __restrict__ Bbf,
    const float* __restrict__ y2g,
    float* __restrict__ cand_s, int* __restrict__ cand_i, int nchunk) {
  __shared__ unsigned short As[128 * 32];  // [row][kgroup(4)][8] bf16
  __shared__ unsigned short Bs[128 * 32];
  __shared__ float Scw[4][64][20];         // per-wave score scratch (16 cols)
  __shared__ float y2sh[256];

  const int tid = threadIdx.x;
  const int w = tid >> 6;
  const int lane = tid & 63;
  const int wr = w >> 1, wc = w & 1;
  const int r0 = blockIdx.y * 128;
  const int c0 = blockIdx.x * 256;

  y2sh[tid] = y2g[c0 + tid];

  // staging: wave w stages rows w*32..w*32+31 of each tile (2 instrs each)
  const int srow = lane >> 2;       // 0..15
  const int skofs = (lane & 3) * 8; // element offset within BK

  float ts[8];
  int ti[8];
#pragma unroll
  for (int j = 0; j < 8; ++j) { ts[j] = SENTINEL; ti[j] = 0x7fffffff; }

  const int arow = wr * 64 + (lane & 15);
  const int brow = wc * 64 + (lane & 15);
  const int kgo = (lane >> 4) * 8;

  for (int t = 0; t < 2; ++t) {
    const int cbase = c0 + t * 128;
    f32x4 acc[4][4];
#pragma unroll
    for (int fi = 0; fi < 4; ++fi)
#pragma unroll
      for (int fj = 0; fj < 4; ++fj) {
        f32x4 z = {0.f, 0.f, 0.f, 0.f};
        acc[fi][fj] = z;
      }

    for (int k0 = 0; k0 < 1024; k0 += BKK) {
      const unsigned short* gA0 =
          Abf + (size_t)(r0 + w * 32 + srow) * 1024 + k0 + skofs;
      const unsigned short* gA1 = gA0 + (size_t)16 * 1024;
      const unsigned short* gB0 =
          Bbf + (size_t)(cbase + w * 32 + srow) * 1024 + k0 + skofs;
      const unsigned short* gB1 = gB0 + (size_t)16 * 1024;
      __syncthreads();  // previous iteration's fragment reads complete
      __builtin_amdgcn_global_load_lds(
          (const __attribute__((address_space(1))) void*)gA0,
          (__attribute__((address_space(3))) void*)&As[w * 1024], 16, 0, 0);
      __builtin_amdgcn_global_load_lds(
          (const __attribute__((address_space(1))) void*)gA1,
          (__attribute__((address_space(3))) void*)&As[w * 1024 + 512], 16, 0, 0);
      __builtin_amdgcn_global_load_lds(
          (const __attribute__((address_space(1))) void*)gB0,
          (__attribute__((address_space(3))) void*)&Bs[w * 1024], 16, 0, 0);
      __builtin_amdgcn_global_load_lds(
          (const __attribute__((address_space(1))) void*)gB1,
          (__attribute__((address_space(3))) void*)&Bs[w * 1024 + 512], 16, 0, 0);
      __syncthreads();  // drain vmcnt: staged data visible

      bf16x8 af[4], bfr[4];
#pragma unroll
      for (int fi = 0; fi < 4; ++fi)
        af[fi] = *(const bf16x8*)&As[(arow + fi * 16) * 32 + kgo];
#pragma unroll
      for (int fj = 0; fj < 4; ++fj)
        bfr[fj] = *(const bf16x8*)&Bs[(brow + fj * 16) * 32 + kgo];
#pragma unroll
      for (int fi = 0; fi < 4; ++fi)
#pragma unroll
        for (int fj = 0; fj < 4; ++fj)
          acc[fi][fj] = __builtin_amdgcn_mfma_f32_16x16x32_bf16(
              af[fi], bfr[fj], acc[fi][fj], 0, 0, 0);
    }

    // epilogue: per fj-group of 16 cols, transpose via LDS, update top-8
    const int scol = lane & 15;
    const int rbase = (lane >> 4) * 4;
#pragma unroll
    for (int fj = 0; fj < 4; ++fj) {
#pragma unroll
      for (int fi = 0; fi < 4; ++fi)
#pragma unroll
        for (int rg = 0; rg < 4; ++rg)
          Scw[w][fi * 16 + rbase + rg][scol] = acc[fi][fj][rg];
      __syncthreads();
      const int cL = t * 128 + wc * 64 + fj * 16;  // block-local col base
      const float4 v0 = *(const float4*)&Scw[w][lane][0];
      const float4 v1 = *(const float4*)&Scw[w][lane][4];
      const float4 v2 = *(const float4*)&Scw[w][lane][8];
      const float4 v3 = *(const float4*)&Scw[w][lane][12];
      float sv[16] = {v0.x, v0.y, v0.z, v0.w, v1.x, v1.y, v1.z, v1.w,
                      v2.x, v2.y, v2.z, v2.w, v3.x, v3.y, v3.z, v3.w};
#pragma unroll
      for (int e = 0; e < 16; ++e) {
        const float s = y2sh[cL + e] - 2.0f * sv[e];
        if (s < ts[7]) {
          ts[7] = s; ti[7] = c0 + cL + e;
#pragma unroll
          for (int j = 7; j > 0; --j) {
            if (ts[j] < ts[j - 1]) {
              const float tss = ts[j]; ts[j] = ts[j - 1]; ts[j - 1] = tss;
              const int tii = ti[j]; ti[j] = ti[j - 1]; ti[j - 1] = tii;
            }
          }
        }
      }
      __syncthreads();
    }
  }

  // write per-(row, chunk, col-half) top-8
  const int rglob = r0 + wr * 64 + lane;
  const size_t base = (((size_t)rglob * nchunk + blockIdx.x) * 2 + wc) * 8;
#pragma unroll
  for (int j = 0; j < 8; ++j) {
    cand_s[base + j] = ts[j];
    cand_i[base + j] = ti[j];
  }
}

// grid: N blocks, 256 threads. 512 candidates -> approx top-16 -> exact
// fp32 rescore -> top-8 -> weighted gather.
__global__ __launch_bounds__(256) void finalize2_kernel(
    const float* __restrict__ A, const float* __restrict__ B,
    const float* __restrict__ y2g,
    const float* __restrict__ cand_s, const int* __restrict__ cand_i,
    float* __restrict__ out) {
  const int n = blockIdx.x;
  const int tid = threadIdx.x;
  const int w = tid >> 6;
  const int lane = tid & 63;
  __shared__ float ms[512];
  __shared__ int mi[512];
  __shared__ int csel[16];
  __shared__ float redw[4][20];
  __shared__ float tot[17];
  __shared__ float wsh[8];
  __shared__ int wci[8];
  __shared__ float invw;

  ms[tid] = cand_s[(size_t)n * 512 + tid];
  ms[tid + 256] = cand_s[(size_t)n * 512 + tid + 256];
  mi[tid] = cand_i[(size_t)n * 512 + tid];
  mi[tid + 256] = cand_i[(size_t)n * 512 + tid + 256];
  __syncthreads();

  if (w == 0) {
    // lane owns slots lane + 64*i; key = (ordered-float(s) << 32) | slot
    unsigned long long key[8];
#pragma unroll
    for (int i = 0; i < 8; ++i) {
      const int slot = lane + 64 * i;
      unsigned u = __float_as_uint(ms[slot]);
      u = (u & 0x80000000u) ? ~u : (u | 0x80000000u);
      key[i] = ((unsigned long long)u << 32) | (unsigned)slot;
    }
    for (int r = 0; r < 16; ++r) {
      unsigned long long kb = key[0];
#pragma unroll
      for (int i = 1; i < 8; ++i) kb = key[i] < kb ? key[i] : kb;
#pragma unroll
      for (int off = 32; off >= 1; off >>= 1) {
        const unsigned long long o = __shfl_xor(kb, off, 64);
        kb = o < kb ? o : kb;
      }
      const int slot = (int)(kb & 0xffffffffu);
      if (lane == 0) csel[r] = slot;
#pragma unroll
      for (int i = 0; i < 8; ++i)
        if (slot == lane + 64 * i) key[i] = ~0ull;
    }
  }
  __syncthreads();

  int ci[16];
#pragma unroll
  for (int j = 0; j < 16; ++j) ci[j] = mi[csel[j]];

  // exact fp32 partial dots (and x2) — thread t handles elements t*4..t*4+3
  const float4 a4 = *(const float4*)&A[(size_t)n * 1024 + tid * 4];
  float part[17];
  part[16] = a4.x * a4.x + a4.y * a4.y + a4.z * a4.z + a4.w * a4.w;
#pragma unroll
  for (int j = 0; j < 16; ++j) {
    const float4 b4 = *(const float4*)&B[(size_t)ci[j] * 1024 + tid * 4];
    part[j] = a4.x * b4.x + a4.y * b4.y + a4.z * b4.z + a4.w * b4.w;
  }
#pragma unroll
  for (int r = 0; r < 17; ++r) {
    float v = part[r];
#pragma unroll
    for (int off = 32; off >= 1; off >>= 1) v += __shfl_xor(v, off, 64);
    if (lane == 0) redw[w][r] = v;
  }
  __syncthreads();
  if (tid < 17) tot[tid] = redw[0][tid] + redw[1][tid] + redw[2][tid] + redw[3][tid];
  __syncthreads();

  if (tid == 0) {
    const float x2 = tot[16];
    float d2v[16];
    bool used[16];
#pragma unroll
    for (int j = 0; j < 16; ++j) {
      d2v[j] = x2 + y2g[ci[j]] - 2.0f * tot[j];
      used[j] = false;
    }
    float wsum = 0.0f;
    for (int k = 0; k < 8; ++k) {
      float bd = SENTINEL;
      int bi = 0x7fffffff, bslot = 0;
      for (int j = 0; j < 16; ++j) {
        if (used[j]) continue;
        const float d2 = d2v[j];
        if (d2 < bd || (d2 == bd && ci[j] < bi)) { bd = d2; bi = ci[j]; bslot = j; }
      }
      used[bslot] = true;
      const float d2c = fmaxf(bd, 1e-12f);
      const float wk = 1.0f / (sqrtf(d2c) + 0.1f);
      wsh[k] = wk;
      wci[k] = bi;
      wsum += wk;
    }
    invw = 1.0f / wsum;
  }
  __syncthreads();

  float ox = 0.f, oy = 0.f, oz = 0.f, ow = 0.f;
#pragma unroll
  for (int k = 0; k < 8; ++k) {
    const float wk = wsh[k];
    const float4 b4 = *(const float4*)&B[(size_t)wci[k] * 1024 + tid * 4];
    ox += wk * b4.x; oy += wk * b4.y; oz += wk * b4.z; ow += wk * b4.w;
  }
  const float iv = invw;
  float4 o;
  o.x = ox * iv; o.y = oy * iv; o.z = oz * iv; o.w = ow * iv;
  *(float4*)&out[(size_t)n * 1024 + tid * 4] = o;
}

// ---------------- fallback path (round-1, verified) ----------------
__global__ __launch_bounds__(256) void knn_chunk_kernel(
    const float* __restrict__ A, const float* __restrict__ B,
    const float* __restrict__ y2g,
    float* __restrict__ cand_s, int* __restrict__ cand_i) {
  __shared__ float As[BKK][68];
  __shared__ float Bs[BKK][68];
  __shared__ float Sc[64][65];

  const int tid = threadIdx.x;
  const int tx = tid & 15;
  const int ty = tid >> 4;
  const int r0 = blockIdx.y * 64;
  const int c0 = blockIdx.x * 1024;
  const int lrow = tid >> 3;
  const int lk = (tid & 7) * 4;

  float top_s[8];
  int top_i[8];
#pragma unroll
  for (int j = 0; j < 8; ++j) { top_s[j] = SENTINEL; top_i[j] = 0x7fffffff; }

  for (int tile = 0; tile < 16; ++tile) {
    const int cbase = c0 + tile * 64;
    float acc[4][4];
#pragma unroll
    for (int i = 0; i < 4; ++i)
#pragma unroll
      for (int j = 0; j < 4; ++j) acc[i][j] = 0.0f;

    for (int k0 = 0; k0 < 1024; k0 += BKK) {
      const float4 a0 = *(const float4*)&A[(size_t)(r0 + lrow) * 1024 + k0 + lk];
      const float4 a1 = *(const float4*)&A[(size_t)(r0 + lrow + 32) * 1024 + k0 + lk];
      const float4 b0 = *(const float4*)&B[(size_t)(cbase + lrow) * 1024 + k0 + lk];
      const float4 b1 = *(const float4*)&B[(size_t)(cbase + lrow + 32) * 1024 + k0 + lk];
      __syncthreads();
      As[lk + 0][lrow] = a0.x; As[lk + 1][lrow] = a0.y;
      As[lk + 2][lrow] = a0.z; As[lk + 3][lrow] = a0.w;
      As[lk + 0][lrow + 32] = a1.x; As[lk + 1][lrow + 32] = a1.y;
      As[lk + 2][lrow + 32] = a1.z; As[lk + 3][lrow + 32] = a1.w;
      Bs[lk + 0][lrow] = b0.x; Bs[lk + 1][lrow] = b0.y;
      Bs[lk + 2][lrow] = b0.z; Bs[lk + 3][lrow] = b0.w;
      Bs[lk + 0][lrow + 32] = b1.x; Bs[lk + 1][lrow + 32] = b1.y;
      Bs[lk + 2][lrow + 32] = b1.z; Bs[lk + 3][lrow + 32] = b1.w;
      __syncthreads();
#pragma unroll
      for (int kk = 0; kk < BKK; ++kk) {
        const float4 av = *(const float4*)&As[kk][ty * 4];
        const float4 bv = *(const float4*)&Bs[kk][tx * 4];
        acc[0][0] += av.x * bv.x; acc[0][1] += av.x * bv.y;
        acc[0][2] += av.x * bv.z; acc[0][3] += av.x * bv.w;
        acc[1][0] += av.y * bv.x; acc[1][1] += av.y * bv.y;
        acc[1][2] += av.y * bv.z; acc[1][3] += av.y * bv.w;
        acc[2][0] += av.z * bv.x; acc[2][1] += av.z * bv.y;
        acc[2][2] += av.z * bv.z; acc[2][3] += av.z * bv.w;
        acc[3][0] += av.w * bv.x; acc[3][1] += av.w * bv.y;
        acc[3][2] += av.w * bv.z; acc[3][3] += av.w * bv.w;
      }
    }
#pragma unroll
    for (int i = 0; i < 4; ++i) {
      const int row = ty * 4 + i;
#pragma unroll
      for (int j = 0; j < 4; ++j) {
        const int col = tx * 4 + j;
        Sc[row][col] = y2g[cbase + col] - 2.0f * acc[i][j];
      }
    }
    __syncthreads();
    if (tid < 64) {
      for (int c = 0; c < 64; ++c) {
        const float s = Sc[tid][c];
        if (s < top_s[7]) {
          top_s[7] = s; top_i[7] = cbase + c;
#pragma unroll
          for (int j = 7; j > 0; --j) {
            if (top_s[j] < top_s[j - 1]) {
              const float tss = top_s[j]; top_s[j] = top_s[j - 1]; top_s[j - 1] = tss;
              const int tii = top_i[j]; top_i[j] = top_i[j - 1]; top_i[j - 1] = tii;
            }
          }
        }
      }
    }
  }

  if (tid < 64) {
    const int n = r0 + tid;
    const int base = (n * gridDim.x + blockIdx.x) * 8;
#pragma unroll
    for (int j = 0; j < 8; ++j) {
      cand_s[base + j] = top_s[j];
      cand_i[base + j] = top_i[j];
    }
  }
}

__global__ __launch_bounds__(256) void finalize_kernel(
    const float* __restrict__ A, const float* __restrict__ B,
    const float* __restrict__ cand_s, const int* __restrict__ cand_i,
    float* __restrict__ out, int nchunks) {
  const int n = blockIdx.x;
  const int tid = threadIdx.x;
  __shared__ float red[256];
  __shared__ float ls[64];
  __shared__ int li[64];
  __shared__ float wsh2[8];
  __shared__ int wid[8];
  __shared__ float wsum_sh;

  const int ncand = nchunks * 8;
  const float4 a = *(const float4*)&A[(size_t)n * 1024 + tid * 4];
  red[tid] = a.x * a.x + a.y * a.y + a.z * a.z + a.w * a.w;
  if (tid < ncand) {
    ls[tid] = cand_s[n * ncand + tid];
    li[tid] = cand_i[n * ncand + tid];
  }
  __syncthreads();
  for (int s = 128; s > 0; s >>= 1) {
    if (tid < s) red[tid] += red[tid + s];
    __syncthreads();
  }
  if (tid == 0) {
    const float x2 = red[0];
    float wsum = 0.0f;
    for (int j = 0; j < 8; ++j) {
      float bs = SENTINEL;
      int bi = 0x7fffffff;
      int bp = 0;
      for (int c = 0; c < ncand; ++c) {
        const float s_ = ls[c];
        const int i_ = li[c];
        if (s_ < bs || (s_ == bs && i_ < bi)) { bs = s_; bi = i_; bp = c; }
      }
      ls[bp] = SENTINEL; li[bp] = 0x7fffffff;
      float d2 = x2 + bs;
      d2 = fmaxf(d2, 1e-12f);
      const float wk = 1.0f / (sqrtf(d2) + 0.1f);
      wsh2[j] = wk; wid[j] = bi;
      wsum += wk;
    }
    wsum_sh = wsum;
  }
  __syncthreads();
  const float inv = 1.0f / wsum_sh;
  float ox = 0.0f, oy = 0.0f, oz = 0.0f, ow = 0.0f;
#pragma unroll
  for (int j = 0; j < 8; ++j) {
    const float wk = wsh2[j];
    const float4 v = *(const float4*)&B[(size_t)wid[j] * 1024 + tid * 4];
    ox += wk * v.x; oy += wk * v.y; oz += wk * v.z; ow += wk * v.w;
  }
  float4 o;
  o.x = ox * inv; o.y = oy * inv; o.z = oz * inv; o.w = ow * inv;
  *(float4*)&out[(size_t)n * 1024 + tid * 4] = o;
}

extern "C" void kernel_launch(void* const* d_in, const int* in_sizes, int n_in,
                              void* d_out, int out_size, void* d_ws, size_t ws_size,
                              hipStream_t stream) {
  const float* A = (const float*)d_in[0];
  const float* Bm = (const float*)d_in[1];
  const int D = 1024;
  const int N = in_sizes[0] / D;  // 4096
  const int M = in_sizes[1] / D;  // 8192

  const size_t needA = (size_t)N * D * 2;
  const size_t needB = (size_t)M * D * 2;
  const size_t needC = (size_t)N * 512 * 4;  // cand_s
  const size_t need = needA + needB + (size_t)M * 4 + 2 * needC;

  if (ws_size >= need && M == 8192 && N % 128 == 0) {
    unsigned short* Abf = (unsigned short*)d_ws;
    unsigned short* Bbf = Abf + (size_t)N * D;
    float* y2 = (float*)(Bbf + (size_t)M * D);
    float* cand_s = y2 + M;
    int* cand_i = (int*)(cand_s + (size_t)N * 512);

    convert_bf16_kernel<<<(N * D / 4 + 255) / 256, 256, 0, stream>>>(A, Abf, N * D / 4);
    convert_bf16_kernel<<<(M * D / 4 + 255) / 256, 256, 0, stream>>>(Bm, Bbf, M * D / 4);
    rownorm_kernel<<<M, 256, 0, stream>>>(Bm, y2);
    dim3 g(M / 256, N / 128);
    screen_kernel<<<g, 256, 0, stream>>>(Abf, Bbf, y2, cand_s, cand_i, M / 256);
    finalize2_kernel<<<N, 256, 0, stream>>>(A, Bm, y2, cand_s, cand_i, (float*)d_out);
  } else {
    float* y2 = (float*)d_ws;
    float* cand_s = y2 + M;
    int* cand_i = (int*)(cand_s + (size_t)N * 64);
    rownorm_kernel<<<M, 256, 0, stream>>>(Bm, y2);
    dim3 gridB(M / 1024, N / 64);
    knn_chunk_kernel<<<gridB, 256, 0, stream>>>(A, Bm, y2, cand_s, cand_i);
    finalize_kernel<<<N, 256, 0, stream>>>(A, Bm, cand_s, cand_i, (float*)d_out, M / 1024);
  }
}